// Round 4
// baseline (805.758 us; speedup 1.0000x reference)
//
#include <hip/hip_runtime.h>

// x: (B=64, L=4096, F=256) fp32
// out = [ d : (64, 4095, 256) ][ y : (64, 4095, 256) ]  flat fp32
//   d[b,l,f] = x[b,l+1,f] - x[b,l,f]
//   y[b,l,f] = x[b,l+1,f] - x[b,0,f]   (l < 4094);  y[b,4094,f] = 0
//
// R4: DIAGNOSTIC — double-launch. R2 (private streams+nt) and R3 (contiguous
// sweep+cached) give IDENTICAL dur_us (~670): kernel time is pattern-invariant
// and unobservable (below top-5 cutoff). Kernel is idempotent, so launching it
// twice is correct and Ddur_us = exactly one kernel execution.
//   H_fast (kernel ~130-150us, already at BW roofline): dur_us ~790-820.
//   H_slow (kernel ~330us, unexplained 2.5TB/s cap):    dur_us ~990-1010,
//     and the kernel enters the top-5 table, exposing its own counters.
// Next round reverts to single launch either way.

typedef float v4f __attribute__((ext_vector_type(4)));

constexpr int B    = 64;
constexpr int L    = 4096;
constexpr int F    = 256;
constexpr int F4   = F / 4;     // 64 float4 per row = exactly one wave
constexpr int LOUT = L - 1;     // 4095 output rows

__global__ __launch_bounds__(256)
void invdiff_kernel(const float* __restrict__ x, float* __restrict__ out) {
    const int lane = threadIdx.x & 63;   // float4 index within row
    const int wave = threadIdx.x >> 6;   // 4 waves per block
    const int b    = blockIdx.y;
    const int l    = blockIdx.x * 4 + wave;   // row index, 0..4095
    if (l >= LOUT) return;               // only block 1023 / wave 3 exits

    const v4f* xb = (const v4f*)(x + (size_t)b * L * F);
    const v4f prev = xb[(size_t)l * F4 + lane];        // x[b, l  ]
    const v4f cur  = xb[(size_t)(l + 1) * F4 + lane];  // x[b, l+1]
    const v4f x0   = xb[lane];                         // x[b, 0] (L2/L3-hot)

    v4f* dout = (v4f*)out + ((size_t)b * LOUT + l) * F4 + lane;
    v4f* yout = dout + (size_t)B * LOUT * F4;

    const v4f zero = {0.f, 0.f, 0.f, 0.f};
    *dout = cur - prev;
    *yout = (l == LOUT - 1) ? zero : cur - x0;
}

extern "C" void kernel_launch(void* const* d_in, const int* in_sizes, int n_in,
                              void* d_out, int out_size, void* d_ws, size_t ws_size,
                              hipStream_t stream) {
    const float* x = (const float*)d_in[0];
    float* out = (float*)d_out;
    // DIAGNOSTIC: two identical launches (idempotent). Delta vs R3's single
    // launch = one kernel execution, resolving H_fast vs H_slow.
    invdiff_kernel<<<dim3(1024, B), dim3(256), 0, stream>>>(x, out);
    invdiff_kernel<<<dim3(1024, B), dim3(256), 0, stream>>>(x, out);
}

// Round 5
// 670.238 us; speedup vs baseline: 1.2022x; 1.2022x over previous
//
#include <hip/hip_runtime.h>

// x: (B=64, L=4096, F=256) fp32
// out = [ d : (64, 4095, 256) ][ y : (64, 4095, 256) ]  flat fp32
//   d[b,l,f] = x[b,l+1,f] - x[b,l,f]
//   y[b,l,f] = x[b,l+1,f] - x[b,0,f]   (l < 4094);  y[b,4094,f] = 0
//   (cumsum telescopes -> closed form, pure streaming kernel)
//
// R5: FINAL — revert R4's diagnostic double-launch to single launch.
// R4 measured Ddur_us = 137us per kernel execution (805.8 double vs 668.8
// single): the kernel moves 805 MB (268 read + 537 write) at 5.9 TB/s
// effective = 93% of the 6.3 TB/s achievable HBM ceiling (harness's own
// 2.1GB fill runs 6.2-6.35 TB/s on the same buffers). Remaining dur_us
// (~530us) is harness-fixed poison-fill work, invariant to the kernel.
// Structure: one wave = one 1KiB row, consecutive blocks sweep consecutive
// addresses (dense moving DRAM fronts); cached loads so the adjacent-wave
// prev/cur overlap is served by L2 (HBM read stays 1x).

typedef float v4f __attribute__((ext_vector_type(4)));

constexpr int B    = 64;
constexpr int L    = 4096;
constexpr int F    = 256;
constexpr int F4   = F / 4;     // 64 float4 per row = exactly one wave
constexpr int LOUT = L - 1;     // 4095 output rows

__global__ __launch_bounds__(256)
void invdiff_kernel(const float* __restrict__ x, float* __restrict__ out) {
    const int lane = threadIdx.x & 63;   // float4 index within row
    const int wave = threadIdx.x >> 6;   // 4 waves per block
    const int b    = blockIdx.y;
    const int l    = blockIdx.x * 4 + wave;   // row index, 0..4095
    if (l >= LOUT) return;               // only block 1023 / wave 3 exits

    const v4f* xb = (const v4f*)(x + (size_t)b * L * F);
    const v4f prev = xb[(size_t)l * F4 + lane];        // x[b, l  ]
    const v4f cur  = xb[(size_t)(l + 1) * F4 + lane];  // x[b, l+1]
    const v4f x0   = xb[lane];                         // x[b, 0] (L2/L3-hot)

    v4f* dout = (v4f*)out + ((size_t)b * LOUT + l) * F4 + lane;
    v4f* yout = dout + (size_t)B * LOUT * F4;

    const v4f zero = {0.f, 0.f, 0.f, 0.f};
    *dout = cur - prev;
    *yout = (l == LOUT - 1) ? zero : cur - x0;
}

extern "C" void kernel_launch(void* const* d_in, const int* in_sizes, int n_in,
                              void* d_out, int out_size, void* d_ws, size_t ws_size,
                              hipStream_t stream) {
    const float* x = (const float*)d_in[0];
    float* out = (float*)d_out;
    // grid: 1024 row-groups (4 rows/block) x 64 batches, 256 threads/block.
    // Dispatch order (x fastest) = consecutive blocks touch consecutive
    // addresses -> dense moving DRAM windows.
    invdiff_kernel<<<dim3(1024, B), dim3(256), 0, stream>>>(x, out);
}